// Round 6
// baseline (23.982 us; speedup 1.0000x reference)
//
#include <hip/hip_runtime.h>

#define THREADS 256
#define WAVES 4                                   // waves per block
#define SPT 2                                     // segments (rounds) per wave
#define SEG 64                                    // systems per wave-segment
#define SYS_PER_BLOCK (THREADS * SPT)             // 512
#define SEG_FLOATS (SEG * 9)                      // 576
#define SEG_VEC4 (SEG_FLOATS / 4)                 // 144
#define BLOCK_VEC4 (SYS_PER_BLOCK * 9 / 4)        // 1152

typedef float vfloat4 __attribute__((ext_vector_type(4)));

// Closed-form 4-point homography (projective basis). Equivalent to the 8x8
// DLT solve for nonsingular systems; verified absmax 0.0625 vs thr 0.795.
__device__ __forceinline__ void solve_h(const vfloat4 c0, const vfloat4 c1,
                                        const vfloat4 e0, const vfloat4 e1,
                                        float h[9])
{
    const float u1 = c0.x, v1 = c0.y, u2 = c0.z, v2 = c0.w;
    const float u3 = c1.x, v3 = c1.y, u4 = c1.z, v4 = c1.w;
    const float p1 = u1 + e0.x, q1 = v1 + e0.y;
    const float p2 = u2 + e0.z, q2 = v2 + e0.w;
    const float p3 = u3 + e1.x, q3 = v3 + e1.y;
    const float p4 = u4 + e1.z, q4 = v4 + e1.w;

    #define DET3(ax,ay,bx,by,cx,cy) \
        (((bx) - (ax)) * ((cy) - (ay)) - ((cx) - (ax)) * ((by) - (ay)))

    const float D1a = DET3(u4, v4, u2, v2, u3, v3);
    const float D2a = DET3(u1, v1, u4, v4, u3, v3);
    const float D3a = DET3(u1, v1, u2, v2, u4, v4);
    const float D1b = DET3(p4, q4, p2, q2, p3, q3);
    const float D2b = DET3(p1, q1, p4, q4, p3, q3);
    const float D3b = DET3(p1, q1, p2, q2, p4, q4);

    const float k1 = D1b * (D2a * D3a);
    const float k2 = D2b * (D3a * D1a);
    const float k3 = D3b * (D1a * D2a);

    const float g1x = v2 - v3, g1y = u3 - u2, g1z = u2 * v3 - u3 * v2;
    const float g2x = v3 - v1, g2y = u1 - u3, g2z = u3 * v1 - u1 * v3;
    const float g3x = v1 - v2, g3y = u2 - u1, g3z = u1 * v2 - u2 * v1;

    const float w1 = k1 * p1, w2 = k2 * p2, w3 = k3 * p3;
    const float x1 = k1 * q1, x2 = k2 * q2, x3 = k3 * q3;

    const float H22 = k1 * g1z + k2 * g2z + k3 * g3z;
    const float r = 1.0f / H22;

    h[0] = (w1 * g1x + w2 * g2x + w3 * g3x) * r;
    h[1] = (w1 * g1y + w2 * g2y + w3 * g3y) * r;
    h[2] = (w1 * g1z + w2 * g2z + w3 * g3z) * r;
    h[3] = (x1 * g1x + x2 * g2x + x3 * g3x) * r;
    h[4] = (x1 * g1y + x2 * g2y + x3 * g3y) * r;
    h[5] = (x1 * g1z + x2 * g2z + x3 * g3z) * r;
    h[6] = (k1 * g1x + k2 * g2x + k3 * g3x) * r;
    h[7] = (k1 * g1y + k2 * g2y + k3 * g3y) * r;
    h[8] = 1.0f;
}

// Barrier-free: the output transpose only crosses lanes WITHIN a wave, so each
// wave gets a private LDS buffer per segment and no __syncthreads is needed.
// Waves free-run -> steady interleaved read/write HBM traffic, no cohort
// phase-locking.
__global__ __launch_bounds__(THREADS) void dlt_kernel(
    const vfloat4* __restrict__ cA,   // corners_A: [B][2] x vfloat4
    const vfloat4* __restrict__ dl,   // delta:     [B][2] x vfloat4
    vfloat4* __restrict__ out4,       // [B*9/4] output
    float* __restrict__ out,          // same buffer, scalar view (tail path)
    int B)
{
    __shared__ float lds[WAVES][SPT][SEG_FLOATS];   // 4*2*576*4 = 18432 B
    const int tid  = threadIdx.x;
    const int lane = tid & 63;
    const int wave = tid >> 6;
    const int blockSysBase = blockIdx.x * SYS_PER_BLOCK;
    // wave w covers systems [blockSysBase + w*SPT*SEG, +SPT*SEG), contiguous
    const int waveSysBase = blockSysBase + wave * (SPT * SEG);

    if (waveSysBase + SPT * SEG <= B) {
        // ---- fast path: full wave segments ----
        const int g0 = waveSysBase + lane;          // segment 0 system
        const int g1 = g0 + SEG;                    // segment 1 system

        // issue all 8 streaming loads up front (max MLP, no reuse -> NT)
        const vfloat4 a00 = __builtin_nontemporal_load(&cA[2 * g0 + 0]);
        const vfloat4 a01 = __builtin_nontemporal_load(&cA[2 * g0 + 1]);
        const vfloat4 d00 = __builtin_nontemporal_load(&dl[2 * g0 + 0]);
        const vfloat4 d01 = __builtin_nontemporal_load(&dl[2 * g0 + 1]);
        const vfloat4 a10 = __builtin_nontemporal_load(&cA[2 * g1 + 0]);
        const vfloat4 a11 = __builtin_nontemporal_load(&cA[2 * g1 + 1]);
        const vfloat4 d10 = __builtin_nontemporal_load(&dl[2 * g1 + 0]);
        const vfloat4 d11 = __builtin_nontemporal_load(&dl[2 * g1 + 1]);

        #pragma unroll
        for (int s = 0; s < SPT; ++s) {
            float h[9];
            if (s == 0) solve_h(a00, a01, d00, d01, h);
            else        solve_h(a10, a11, d10, d11, h);

            float* buf = &lds[wave][s][0];
            // stride-9 writes: odd stride -> <=2 lanes/bank, free (m136)
            #pragma unroll
            for (int k = 0; k < 9; ++k) buf[lane * 9 + k] = h[k];
            // wave-synchronous: same-wave DS ordering (lgkmcnt) suffices, no barrier

            const vfloat4* buf4 = (const vfloat4*)buf;
            const int segBase4 = (waveSysBase + s * SEG) * 9 / 4;  // *144 per seg
            // 144 vec4 per segment: lanes 0..63 do i, i+64; lanes 0..15 do i+128
            __builtin_nontemporal_store(buf4[lane],      &out4[segBase4 + lane]);
            __builtin_nontemporal_store(buf4[lane + 64], &out4[segBase4 + lane + 64]);
            if (lane < SEG_VEC4 - 128)
                __builtin_nontemporal_store(buf4[lane + 128], &out4[segBase4 + lane + 128]);
        }
    } else {
        // ---- tail path: guarded scalar (never taken for B % 512 == 0) ----
        #pragma unroll
        for (int s = 0; s < SPT; ++s) {
            const int b = waveSysBase + s * SEG + lane;
            if (b < B) {
                const vfloat4 c0 = cA[2 * b + 0];
                const vfloat4 c1 = cA[2 * b + 1];
                const vfloat4 e0 = dl[2 * b + 0];
                const vfloat4 e1 = dl[2 * b + 1];
                float h[9];
                solve_h(c0, c1, e0, e1, h);
                #pragma unroll
                for (int k = 0; k < 9; ++k) out[b * 9 + k] = h[k];
            }
        }
    }
}

extern "C" void kernel_launch(void* const* d_in, const int* in_sizes, int n_in,
                              void* d_out, int out_size, void* d_ws, size_t ws_size,
                              hipStream_t stream) {
    const int B = in_sizes[0] / 8;  // corners_A: [B,4,2] floats
    const vfloat4* cA = (const vfloat4*)d_in[0];
    const vfloat4* dl = (const vfloat4*)d_in[1];
    vfloat4* out4 = (vfloat4*)d_out;
    float* out = (float*)d_out;
    const int grid = (B + SYS_PER_BLOCK - 1) / SYS_PER_BLOCK;
    dlt_kernel<<<grid, THREADS, 0, stream>>>(cA, dl, out4, out, B);
}

// Round 7
// 20.772 us; speedup vs baseline: 1.1545x; 1.1545x over previous
//
#include <hip/hip_runtime.h>

#define THREADS 256
#define WAVE_SYS 64                         // systems per wave
#define BLOCK_FLOATS (THREADS * 9)          // 2304
#define BLOCK_VEC4 (BLOCK_FLOATS / 4)       // 576

typedef float vfloat4 __attribute__((ext_vector_type(4)));

__device__ __forceinline__ vfloat4 shflx1_v4(vfloat4 v) {
    vfloat4 r;
    r.x = __shfl_xor(v.x, 1, 64);
    r.y = __shfl_xor(v.y, 1, 64);
    r.z = __shfl_xor(v.z, 1, 64);
    r.w = __shfl_xor(v.w, 1, 64);
    return r;
}

// Closed-form 4-point homography (projective basis). Equivalent to the 8x8
// DLT solve for nonsingular systems; verified absmax 0.0625 vs thr 0.795.
__device__ __forceinline__ void solve_h(const vfloat4 c0, const vfloat4 c1,
                                        const vfloat4 e0, const vfloat4 e1,
                                        float h[9])
{
    const float u1 = c0.x, v1 = c0.y, u2 = c0.z, v2 = c0.w;
    const float u3 = c1.x, v3 = c1.y, u4 = c1.z, v4 = c1.w;
    const float p1 = u1 + e0.x, q1 = v1 + e0.y;
    const float p2 = u2 + e0.z, q2 = v2 + e0.w;
    const float p3 = u3 + e1.x, q3 = v3 + e1.y;
    const float p4 = u4 + e1.z, q4 = v4 + e1.w;

    #define DET3(ax,ay,bx,by,cx,cy) \
        (((bx) - (ax)) * ((cy) - (ay)) - ((cx) - (ax)) * ((by) - (ay)))

    const float D1a = DET3(u4, v4, u2, v2, u3, v3);
    const float D2a = DET3(u1, v1, u4, v4, u3, v3);
    const float D3a = DET3(u1, v1, u2, v2, u4, v4);
    const float D1b = DET3(p4, q4, p2, q2, p3, q3);
    const float D2b = DET3(p1, q1, p4, q4, p3, q3);
    const float D3b = DET3(p1, q1, p2, q2, p4, q4);

    const float k1 = D1b * (D2a * D3a);
    const float k2 = D2b * (D3a * D1a);
    const float k3 = D3b * (D1a * D2a);

    const float g1x = v2 - v3, g1y = u3 - u2, g1z = u2 * v3 - u3 * v2;
    const float g2x = v3 - v1, g2y = u1 - u3, g2z = u3 * v1 - u1 * v3;
    const float g3x = v1 - v2, g3y = u2 - u1, g3z = u1 * v2 - u2 * v1;

    const float w1 = k1 * p1, w2 = k2 * p2, w3 = k3 * p3;
    const float x1 = k1 * q1, x2 = k2 * q2, x3 = k3 * q3;

    const float H22 = k1 * g1z + k2 * g2z + k3 * g3z;
    const float r = 1.0f / H22;

    h[0] = (w1 * g1x + w2 * g2x + w3 * g3x) * r;
    h[1] = (w1 * g1y + w2 * g2y + w3 * g3y) * r;
    h[2] = (w1 * g1z + w2 * g2z + w3 * g3z) * r;
    h[3] = (x1 * g1x + x2 * g2x + x3 * g3x) * r;
    h[4] = (x1 * g1y + x2 * g2y + x3 * g3y) * r;
    h[5] = (x1 * g1z + x2 * g2z + x3 * g3z) * r;
    h[6] = (k1 * g1x + k2 * g2x + k3 * g3x) * r;
    h[7] = (k1 * g1y + k2 * g2y + k3 * g3y) * r;
    h[8] = 1.0f;
}

// R2 structure (best measured) + contiguous input loads.
// Loads: lane l takes vec4 (base+l) and (base+64+l) -> 16 segments/instr
// (vs 32 for the old stride-32B pattern), then a lane^1 DPP exchange gives
// each lane one full system: even lane -> sys j, odd lane -> sys 32+j.
__global__ __launch_bounds__(THREADS) void dlt_kernel(
    const vfloat4* __restrict__ cA4,   // corners_A: [2B] vec4
    const vfloat4* __restrict__ dl4,   // delta:     [2B] vec4
    vfloat4* __restrict__ out4,        // [B*9/4]
    float* __restrict__ out,           // scalar view (tail)
    int B)
{
    __shared__ float lds[BLOCK_FLOATS];
    const int tid  = threadIdx.x;
    const int lane = tid & 63;
    const int wave = tid >> 6;
    const int blockSysBase = blockIdx.x * THREADS;
    const int waveSysBase  = blockSysBase + wave * WAVE_SYS;
    const bool odd = (lane & 1) != 0;
    const int sysLocal = (lane >> 1) + (odd ? 32 : 0);   // system within wave

    const bool fullWave = (waveSysBase + WAVE_SYS) <= B;
    float h[9];
    #pragma unroll
    for (int k = 0; k < 9; ++k) h[k] = 0.0f;

    if (fullWave) {
        const int vb = 2 * waveSysBase;
        // perfectly coalesced: consecutive lanes -> consecutive vec4
        const vfloat4 rA0 = cA4[vb + lane];
        const vfloat4 rA1 = cA4[vb + 64 + lane];
        const vfloat4 rD0 = dl4[vb + lane];
        const vfloat4 rD1 = dl4[vb + 64 + lane];

        // neighbor exchange: even lanes send r1, odd lanes send r0
        const vfloat4 tA = shflx1_v4(odd ? rA0 : rA1);
        const vfloat4 tD = shflx1_v4(odd ? rD0 : rD1);

        // even lane 2j: sys j   = {rA0, tA}; odd lane 2j+1: sys 32+j = {tA, rA1}
        const vfloat4 c0 = odd ? tA : rA0;
        const vfloat4 c1 = odd ? rA1 : tA;
        const vfloat4 e0 = odd ? tD : rD0;
        const vfloat4 e1 = odd ? rD1 : tD;

        solve_h(c0, c1, e0, e1, h);
    } else {
        const int b = waveSysBase + sysLocal;
        if (b < B) {
            const vfloat4 c0 = cA4[2 * b + 0];
            const vfloat4 c1 = cA4[2 * b + 1];
            const vfloat4 e0 = dl4[2 * b + 0];
            const vfloat4 e1 = dl4[2 * b + 1];
            solve_h(c0, c1, e0, e1, h);
        }
    }

    // stride-9 LDS writes at permuted indices: odd stride -> <=2 lanes/bank
    float* buf = &lds[wave * (WAVE_SYS * 9)];
    #pragma unroll
    for (int k = 0; k < 9; ++k) buf[sysLocal * 9 + k] = h[k];
    __syncthreads();

    // coalesced stores: block's 2304 floats = 576 vec4
    if ((blockSysBase + THREADS) <= B) {
        const vfloat4* l4 = (const vfloat4*)lds;
        const int base4 = blockIdx.x * BLOCK_VEC4;
        #pragma unroll
        for (int k = 0; k < 3; ++k) {          // 2.25 iters: 256,256,64
            const int i = k * THREADS + tid;
            if (i < BLOCK_VEC4)
                __builtin_nontemporal_store(l4[i], &out4[base4 + i]);
        }
    } else {
        const int baseF = blockSysBase * 9;
        const int totalF = B * 9;
        for (int i = tid; i < BLOCK_FLOATS; i += THREADS) {
            const int gi = baseF + i;
            if (gi < totalF) out[gi] = lds[i];
        }
    }
}

extern "C" void kernel_launch(void* const* d_in, const int* in_sizes, int n_in,
                              void* d_out, int out_size, void* d_ws, size_t ws_size,
                              hipStream_t stream) {
    const int B = in_sizes[0] / 8;  // corners_A: [B,4,2] floats
    const vfloat4* cA4 = (const vfloat4*)d_in[0];
    const vfloat4* dl4 = (const vfloat4*)d_in[1];
    vfloat4* out4 = (vfloat4*)d_out;
    float* out = (float*)d_out;
    const int grid = (B + THREADS - 1) / THREADS;
    dlt_kernel<<<grid, THREADS, 0, stream>>>(cA4, dl4, out4, out, B);
}